// Round 2
// baseline (582.068 us; speedup 1.0000x reference)
//
#include <hip/hip_runtime.h>

typedef unsigned short u16;
typedef unsigned int u32;

#define B_   64
#define C_   256
#define L_   4096
#define NH   8
#define NQ   16
#define DH   32
#define HQ   128
#define FHN  512
#define EPS_ 1e-6f

// ---- workspace layout (bytes), ~10.1 MB ----
#define WS_WC    0            // u16 [128][32]               8192
#define WS_SWG   8192         // f32 [128]                    512
#define WS_CB    8704         // f32 [128]                    512
#define WS_VGC   9216         // u16 [256][256]            131072
#define WS_WG1   140288       // f32 [256]                   1024
#define WS_WB1   141312       // f32 [256]                   1024
#define WS_DENP  142336       // f32 [8][8192]             262144
#define WS_SNUP  404480       // f32 [8][8192]             262144
#define WS_A     666624       // f32 [64][128][32]        1048576
#define WS_APART 1715200      // f32 [8][64][128][32]     8388608

typedef __attribute__((ext_vector_type(8))) short bf16x8;
typedef __attribute__((ext_vector_type(4))) float f32x4;

__device__ __forceinline__ u16 f32_to_bf16(float f) {
    u32 u = __float_as_uint(f);
    u32 r = u + 0x7fffu + ((u >> 16) & 1u);   // RNE
    return (u16)(r >> 16);
}
__device__ __forceinline__ float bf16_to_f32(u16 h) {
    return __uint_as_float(((u32)h) << 16);
}
__device__ __forceinline__ u32 pk2(u16 lo, u16 hi) {
    return (u32)lo | ((u32)hi << 16);
}

// ---------------------------------------------------------------------------
// k_prep: wc[hq][32] = bf16(attn_w * gamma_slice); Swg = sum of the bf16 vals
// (fp32) so the mu-correction matches the MFMA operand exactly; Cb = w.beta.
// ---------------------------------------------------------------------------
__global__ __launch_bounds__(256) void k_prep(
    const float* __restrict__ attn_w, const float* __restrict__ gamma,
    const float* __restrict__ beta, u16* __restrict__ wc,
    float* __restrict__ Swg, float* __restrict__ Cb)
{
    int t = threadIdx.x;
    if (t >= HQ) return;
    int h = t >> 4;
    float sw = 0.f, cb = 0.f;
    for (int c = 0; c < DH; c++) {
        float w = attn_w[t * DH + c];
        u16 hb = f32_to_bf16(w * gamma[h * DH + c]);
        wc[t * DH + c] = hb;
        sw += bf16_to_f32(hb);
        cb += w * beta[h * DH + c];
    }
    Swg[t] = sw;
    Cb[t] = cb;
}

// ---------------------------------------------------------------------------
// k_prepv: VGc[e][c] = bf16(val_w[e][c]*gamma[c]) for the epilogue MFMA;
// Wg1[e] = sum_c of the bf16 values (exact mu-cancellation), Wb1[e] = w.beta.
// ---------------------------------------------------------------------------
__global__ __launch_bounds__(256) void k_prepv(
    const float* __restrict__ val_w, const float* __restrict__ gamma,
    const float* __restrict__ beta, u16* __restrict__ VGc,
    float* __restrict__ Wg1, float* __restrict__ Wb1)
{
    int t = threadIdx.x;
    int e = blockIdx.x * 4 + (t >> 6);
    int lane = t & 63;
    float4 w  = *(const float4*)(val_w + (size_t)e * C_ + lane * 4);
    float4 g  = *(const float4*)(gamma + lane * 4);
    float4 bt = *(const float4*)(beta + lane * 4);
    u16 h0 = f32_to_bf16(w.x * g.x);
    u16 h1 = f32_to_bf16(w.y * g.y);
    u16 h2 = f32_to_bf16(w.z * g.z);
    u16 h3 = f32_to_bf16(w.w * g.w);
    uint2 pk;
    pk.x = pk2(h0, h1);
    pk.y = pk2(h2, h3);
    *(uint2*)(VGc + (size_t)e * C_ + lane * 4) = pk;
    float sg = bf16_to_f32(h0) + bf16_to_f32(h1) + bf16_to_f32(h2) + bf16_to_f32(h3);
    float sb = w.x * bt.x + w.y * bt.y + w.z * bt.z + w.w * bt.w;
    #pragma unroll
    for (int off = 1; off < 64; off <<= 1) {
        sg += __shfl_xor(sg, off);
        sb += __shfl_xor(sb, off);
    }
    if (lane == 0) { Wg1[e] = sg; Wb1[e] = sb; }
}

// ---------------------------------------------------------------------------
// k_fused (8-wave rev): per (ks,b) block of 512 threads over a 512-l slice,
// chunked by 32 l. Per chunk, 3 phases:
//   A: write XC(k) from pr, stats from XT(k)            | barrier
//   B: logits MFMA -> exp -> EA; cvt fr->pr; load k+2   | barrier
//   C: GEMM (EA x XC) into acc; write XT(k+1) from pr   | barrier
// acc[4][4] per lane (64 VGPR) -> 16 waves/CU with __launch_bounds__(512,4).
// XC single-buffered; LDS pool 41.7 KB. Epilogue projects Praw -> Apart via
// VGc MFMA in two 64-row halves (P reuses the pool).
// ---------------------------------------------------------------------------
__global__ __launch_bounds__(512, 4) void k_fused(
    const float* __restrict__ x, const u16* __restrict__ wc,
    const float* __restrict__ Swg, const float* __restrict__ Cb,
    const u16* __restrict__ VGc, float* __restrict__ Apart,
    float* __restrict__ DenP, float* __restrict__ SnuP)
{
    // pool: main loop {XT 16896 | EA 9216 | XC 16384} = 42496 B
    //       epilogue  {P 64*264*2 = 33792 B} (reuse)
    __shared__ __align__(16) char POOL[42496];
    u16* const XT = (u16*)POOL;            // [32][264]
    u16* const EA = (u16*)(POOL + 16896);  // [128][36]
    u16* const XC = (u16*)(POOL + 26112);  // [256][32] swizzled
    __shared__ float smu[32], srs[32];
    int t = threadIdx.x;
    int lane = t & 63, wv = t >> 6;        // wv 0..7
    int lane15 = lane & 15, quad = lane >> 4;
    int ks = blockIdx.x, b = blockIdx.y;
    int lbase = ks * 512;
    int m0 = (wv & 1) * 64, n0 = (wv >> 1) * 64;
    int c_own = t & 255, hh = t >> 8;      // staging: channel + l-half

    // logits constants: one head per wave
    int h = wv;
    bf16x8 af = *(const bf16x8*)(wc + (size_t)(h * 16 + lane15) * DH + quad * 8);
    float swr[4], cbr[4];
    #pragma unroll
    for (int r = 0; r < 4; r++) {
        int hq = h * 16 + quad * 4 + r;
        swr[r] = Swg[hq];
        cbr[r] = Cb[hq];
    }

    const float* xR = x + ((size_t)b * C_ + c_own) * L_ + lbase + hh * 16;

    float4 fr[4];       // fp32 prefetch: 16 l of channel c_own
    uint4 pr[2];        // packed bf16 for one chunk (16 l)
    auto loadregs = [&](int k) {
        #pragma unroll
        for (int i = 0; i < 4; i++) fr[i] = *(const float4*)(xR + k * 32 + i * 4);
    };
    auto cvtregs = [&]() {
        const float* pf = (const float*)fr;
        u16 hb[16];
        #pragma unroll
        for (int e = 0; e < 16; e++) hb[e] = f32_to_bf16(pf[e]);
        #pragma unroll
        for (int i = 0; i < 2; i++) {
            uint4 w;
            w.x = pk2(hb[i * 8 + 0], hb[i * 8 + 1]);
            w.y = pk2(hb[i * 8 + 2], hb[i * 8 + 3]);
            w.z = pk2(hb[i * 8 + 4], hb[i * 8 + 5]);
            w.w = pk2(hb[i * 8 + 6], hb[i * 8 + 7]);
            pr[i] = w;
        }
    };
    auto write_xc = [&]() {
        #pragma unroll
        for (int i = 0; i < 2; i++) {
            int g = hh * 2 + i;
            *(uint4*)&XC[c_own * 32 + ((g ^ ((c_own >> 1) & 3)) * 8)] = pr[i];
        }
    };
    auto write_xt = [&]() {
        const u16* ph = (const u16*)pr;
        #pragma unroll
        for (int e = 0; e < 16; e++) XT[(hh * 16 + e) * 264 + c_own] = ph[e];
    };

    f32x4 acc[4][4];
    #pragma unroll
    for (int i = 0; i < 4; i++)
        #pragma unroll
        for (int j = 0; j < 4; j++) {
            f32x4 z = {0.f, 0.f, 0.f, 0.f};
            acc[i][j] = z;
        }
    float se[4] = {}, sm[4] = {};

    int l_loc = t >> 4, g16 = t & 15;   // stats: 16 threads per l

    loadregs(0);
    cvtregs();          // pr = chunk 0
    write_xt();         // XT(0)
    loadregs(1);        // fr = chunk 1
    __syncthreads();

    for (int k = 0; k < 16; k++) {
        // ---- phase A: XC(k) from pr; stats(k) from XT ----
        write_xc();
        {
            const u16* row = XT + l_loc * 264 + g16 * 16;
            float s = 0.f, q = 0.f;
            #pragma unroll
            for (int j = 0; j < 2; j++) {
                uint4 v = *(const uint4*)(row + j * 8);
                u32 ww[4] = {v.x, v.y, v.z, v.w};
                #pragma unroll
                for (int e = 0; e < 4; e++) {
                    float f0 = __uint_as_float(ww[e] << 16);
                    float f1 = __uint_as_float(ww[e] & 0xffff0000u);
                    s += f0 + f1;
                    q += f0 * f0 + f1 * f1;
                }
            }
            #pragma unroll
            for (int off = 1; off < 16; off <<= 1) {
                s += __shfl_xor(s, off);
                q += __shfl_xor(q, off);
            }
            if (g16 == 0) {
                float mm = s * (1.f / C_);
                float vv = fmaxf(q * (1.f / C_) - mm * mm, 0.f) + EPS_;
                smu[l_loc] = mm;
                srs[l_loc] = rsqrtf(vv);
            }
        }
        __syncthreads();

        // ---- phase B: logits MFMA -> exp -> EA; cvt + prefetch ----
        #pragma unroll
        for (int half = 0; half < 2; half++) {
            float m_l = smu[half * 16 + lane15];
            float r_l = srs[half * 16 + lane15];
            bf16x8 bfrag = *(const bf16x8*)(XT + (half * 16 + lane15) * 264 + h * DH + quad * 8);
            f32x4 z = {0.f, 0.f, 0.f, 0.f};
            f32x4 c4 = __builtin_amdgcn_mfma_f32_16x16x32_bf16(af, bfrag, z, 0, 0, 0);
            #pragma unroll
            for (int r = 0; r < 4; r++) {
                float logit = r_l * (c4[r] - m_l * swr[r]) + cbr[r];
                float e = __expf(logit);     // logits ~N(0,1): no max-sub needed
                float ers = e * r_l;
                EA[(h * 16 + quad * 4 + r) * 36 + half * 16 + lane15] = f32_to_bf16(ers);
                se[r] += e;
                sm[r] += ers * m_l;
            }
        }
        if (k < 15) cvtregs();          // pr = chunk k+1
        if (k < 14) loadregs(k + 2);    // fr = chunk k+2
        __syncthreads();

        // ---- phase C: GEMM(k) + stage XT(k+1) ----
        bf16x8 a[4];
        #pragma unroll
        for (int i = 0; i < 4; i++)
            a[i] = *(const bf16x8*)&EA[(m0 + i * 16 + lane15) * 36 + quad * 8];
        #pragma unroll
        for (int j = 0; j < 4; j++) {
            int row = n0 + j * 16 + lane15;
            bf16x8 bbj = *(const bf16x8*)&XC[row * 32 + ((quad ^ ((row >> 1) & 3)) * 8)];
            #pragma unroll
            for (int i = 0; i < 4; i++)
                acc[i][j] = __builtin_amdgcn_mfma_f32_16x16x32_bf16(a[i], bbj, acc[i][j], 0, 0, 0);
        }
        if (k < 15) write_xt();         // XT(k+1)
        __syncthreads();
    }

    // ---- epilogue: Praw -> bf16 P (two 64-row halves) -> MFMA VGc -> Apart
    u16* const P = (u16*)POOL;   // [64][264], reuses the whole pool
    float* ApB = Apart + (((size_t)ks * B_ + b) * HQ) * DH;
    #pragma unroll
    for (int half = 0; half < 2; half++) {
        if ((wv & 1) == half) {
            #pragma unroll
            for (int i = 0; i < 4; i++)
                #pragma unroll
                for (int j = 0; j < 4; j++) {
                    int lr = i * 16 + quad * 4;
                    int col = n0 + j * 16 + lane15;
                    #pragma unroll
                    for (int r = 0; r < 4; r++)
                        P[(lr + r) * 264 + col] = f32_to_bf16(acc[i][j][r]);
                }
        }
        __syncthreads();
        {
            int hl = wv >> 1;                 // 0..3
            int he = half * 4 + hl;           // head for this task
            int dt = wv & 1;                  // d-tile
            f32x4 c2 = {0.f, 0.f, 0.f, 0.f};
            #pragma unroll
            for (int kk = 0; kk < 8; kk++) {
                bf16x8 a = *(const bf16x8*)&P[(hl * 16 + lane15) * 264 + kk * 32 + quad * 8];
                bf16x8 vg = *(const bf16x8*)(VGc + (size_t)(he * DH + dt * 16 + lane15) * C_ + kk * 32 + quad * 8);
                c2 = __builtin_amdgcn_mfma_f32_16x16x32_bf16(a, vg, c2, 0, 0, 0);
            }
            #pragma unroll
            for (int r = 0; r < 4; r++)
                ApB[(size_t)(he * 16 + quad * 4 + r) * DH + dt * 16 + lane15] = c2[r];
        }
        __syncthreads();
    }

    // ---- softmax partial sums: reduce over lane15, one store per row ----
    #pragma unroll
    for (int r = 0; r < 4; r++) {
        float v = se[r], w = sm[r];
        #pragma unroll
        for (int off = 1; off < 16; off <<= 1) {
            v += __shfl_xor(v, off);
            w += __shfl_xor(w, off);
        }
        if (lane15 == 0) {
            int row = b * HQ + wv * 16 + quad * 4 + r;
            DenP[ks * (B_ * HQ) + row] = v;
            SnuP[ks * (B_ * HQ) + row] = w;
        }
    }
}

// ---------------------------------------------------------------------------
// k_reduce: A[b][hq][d] = (sum_s Apart - SnuTot*Wg1[hd]) / DenTot
//           + Wb1[hd] + val_b[hd]       (beta term: se/den == 1)
// ---------------------------------------------------------------------------
__global__ __launch_bounds__(256) void k_reduce(
    const float* __restrict__ Apart, const float* __restrict__ DenP,
    const float* __restrict__ SnuP, const float* __restrict__ Wg1,
    const float* __restrict__ Wb1, const float* __restrict__ val_b,
    float* __restrict__ A)
{
    __shared__ float sden[32], ssnu[32];
    int t = threadIdx.x;
    int q4 = blockIdx.x, b = blockIdx.y;
    int hq0 = q4 * 32;
    if (t < 32) {
        int row = b * HQ + hq0 + t;
        float d = 0.f, sn = 0.f;
        #pragma unroll
        for (int s = 0; s < 8; s++) {
            d  += DenP[s * (B_ * HQ) + row];
            sn += SnuP[s * (B_ * HQ) + row];
        }
        sden[t] = d;
        ssnu[t] = sn;
    }
    __syncthreads();
    #pragma unroll
    for (int i = 0; i < 4; i++) {
        int idx = i * 256 + t;
        int r32 = idx >> 5, d = idx & 31;
        int hq = hq0 + r32;
        float v = 0.f;
        #pragma unroll
        for (int s = 0; s < 8; s++)
            v += Apart[(((size_t)s * B_ + b) * HQ + hq) * DH + d];
        int hd = (hq >> 4) * DH + d;
        A[((size_t)b * HQ + hq) * DH + d] =
            (v - ssnu[r32] * Wg1[hd]) / sden[r32] + Wb1[hd] + val_b[hd];
    }
}

// ---------------------------------------------------------------------------
// k_final: out[b][f] = sum_j A[b][j]*fin_w[f][j] + fin_b[f]
// grid (32,16), block 256; k-split atomicAdd (out pre-zeroed).
// ---------------------------------------------------------------------------
__global__ __launch_bounds__(256) void k_final(
    const float* __restrict__ A, const float* __restrict__ fin_w,
    const float* __restrict__ fin_b, float* __restrict__ out)
{
    __shared__ float At[64 * 129];
    __shared__ float Fw[32 * 129];
    int t = threadIdx.x;
    int kc = blockIdx.x, ft = blockIdx.y;
    int k0 = kc * 128;

    #pragma unroll
    for (int w = 0; w < 8; w++) {
        int s = t + w * 256;
        int row = s >> 5, seg = s & 31;
        float4 v = *(const float4*)(A + (size_t)row * 4096 + k0 + seg * 4);
        const float* pf = (const float*)&v;
        #pragma unroll
        for (int e = 0; e < 4; e++) At[row * 129 + seg * 4 + e] = pf[e];
    }
    #pragma unroll
    for (int w = 0; w < 4; w++) {
        int s = t + w * 256;
        int row = s >> 5, seg = s & 31;
        float4 v = *(const float4*)(fin_w + (size_t)(ft * 32 + row) * 4096 + k0 + seg * 4);
        const float* pf = (const float*)&v;
        #pragma unroll
        for (int e = 0; e < 4; e++) Fw[row * 129 + seg * 4 + e] = pf[e];
    }
    __syncthreads();

    int tb = t >> 3, tf = t & 7;
    float acc[2][4];
    #pragma unroll
    for (int e = 0; e < 2; e++)
        #pragma unroll
        for (int j = 0; j < 4; j++) acc[e][j] = 0.f;

    for (int k = 0; k < 128; k++) {
        float a0 = At[(tb * 2) * 129 + k];
        float a1 = At[(tb * 2 + 1) * 129 + k];
        #pragma unroll
        for (int j = 0; j < 4; j++) {
            float f = Fw[(tf * 4 + j) * 129 + k];
            acc[0][j] += a0 * f;
            acc[1][j] += a1 * f;
        }
    }
    #pragma unroll
    for (int e = 0; e < 2; e++) {
        int brow = tb * 2 + e;
        #pragma unroll
        for (int j = 0; j < 4; j++) {
            int f = ft * 32 + tf * 4 + j;
            float v = acc[e][j];
            if (kc == 0) v += fin_b[f];
            atomicAdd(&out[(size_t)brow * FHN + f], v);
        }
    }
}

extern "C" void kernel_launch(void* const* d_in, const int* in_sizes, int n_in,
                              void* d_out, int out_size, void* d_ws, size_t ws_size,
                              hipStream_t stream) {
    const float* x      = (const float*)d_in[0];
    const float* gamma  = (const float*)d_in[1];
    const float* beta   = (const float*)d_in[2];
    const float* attn_w = (const float*)d_in[3];
    const float* val_w  = (const float*)d_in[4];
    const float* val_b  = (const float*)d_in[5];
    const float* fin_w  = (const float*)d_in[6];
    const float* fin_b  = (const float*)d_in[7];
    float* out = (float*)d_out;
    char* ws = (char*)d_ws;

    u16*   wc    = (u16*)(ws + WS_WC);
    float* Swg   = (float*)(ws + WS_SWG);
    float* Cb    = (float*)(ws + WS_CB);
    u16*   VGc   = (u16*)(ws + WS_VGC);
    float* Wg1   = (float*)(ws + WS_WG1);
    float* Wb1   = (float*)(ws + WS_WB1);
    float* DenP  = (float*)(ws + WS_DENP);
    float* SnuP  = (float*)(ws + WS_SNUP);
    float* A     = (float*)(ws + WS_A);
    float* Apart = (float*)(ws + WS_APART);

    hipMemsetAsync(out, 0, (size_t)B_ * FHN * sizeof(float), stream);

    k_prep<<<dim3(1), dim3(256), 0, stream>>>(attn_w, gamma, beta, wc, Swg, Cb);
    k_prepv<<<dim3(64), dim3(256), 0, stream>>>(val_w, gamma, beta, VGc, Wg1, Wb1);
    k_fused<<<dim3(8, 64), dim3(512), 0, stream>>>(x, wc, Swg, Cb, VGc, Apart,
                                                   DenP, SnuP);
    k_reduce<<<dim3(4, 64), dim3(256), 0, stream>>>(Apart, DenP, SnuP, Wg1, Wb1,
                                                    val_b, A);
    k_final<<<dim3(32, 16), dim3(256), 0, stream>>>(A, fin_w, fin_b, out);
}

// Round 3
// 441.231 us; speedup vs baseline: 1.3192x; 1.3192x over previous
//
#include <hip/hip_runtime.h>

typedef unsigned short u16;
typedef unsigned int u32;

#define B_   64
#define C_   256
#define L_   4096
#define NH   8
#define NQ   16
#define DH   32
#define HQ   128
#define FHN  512
#define EPS_ 1e-6f

// ---- workspace layout (bytes), ~10.1 MB ----
#define WS_WC    0            // u16 [128][32]               8192
#define WS_SWG   8192         // f32 [128]                    512
#define WS_CB    8704         // f32 [128]                    512
#define WS_VGC   9216         // u16 [256][256]            131072
#define WS_WG1   140288       // f32 [256]                   1024
#define WS_WB1   141312       // f32 [256]                   1024
#define WS_DENP  142336       // f32 [8][8192]             262144
#define WS_SNUP  404480       // f32 [8][8192]             262144
#define WS_A     666624       // f32 [64][128][32]        1048576
#define WS_APART 1715200      // f32 [8][64][128][32]     8388608

typedef __attribute__((ext_vector_type(8))) short bf16x8;
typedef __attribute__((ext_vector_type(4))) float f32x4;

__device__ __forceinline__ u16 f32_to_bf16(float f) {
    u32 u = __float_as_uint(f);
    u32 r = u + 0x7fffu + ((u >> 16) & 1u);   // RNE
    return (u16)(r >> 16);
}
__device__ __forceinline__ float bf16_to_f32(u16 h) {
    return __uint_as_float(((u32)h) << 16);
}
__device__ __forceinline__ u32 pk2(u16 lo, u16 hi) {
    return (u32)lo | ((u32)hi << 16);
}

// ---------------------------------------------------------------------------
// k_prep: wc[hq][32] = bf16(attn_w * gamma_slice); Swg = sum of the bf16 vals
// (fp32) so the mu-correction matches the MFMA operand exactly; Cb = w.beta.
// ---------------------------------------------------------------------------
__global__ __launch_bounds__(256) void k_prep(
    const float* __restrict__ attn_w, const float* __restrict__ gamma,
    const float* __restrict__ beta, u16* __restrict__ wc,
    float* __restrict__ Swg, float* __restrict__ Cb)
{
    int t = threadIdx.x;
    if (t >= HQ) return;
    int h = t >> 4;
    float sw = 0.f, cb = 0.f;
    for (int c = 0; c < DH; c++) {
        float w = attn_w[t * DH + c];
        u16 hb = f32_to_bf16(w * gamma[h * DH + c]);
        wc[t * DH + c] = hb;
        sw += bf16_to_f32(hb);
        cb += w * beta[h * DH + c];
    }
    Swg[t] = sw;
    Cb[t] = cb;
}

// ---------------------------------------------------------------------------
// k_prepv: VGc[e][c] = bf16(val_w[e][c]*gamma[c]) for the epilogue MFMA;
// Wg1[e] = sum_c of the bf16 values (exact mu-cancellation), Wb1[e] = w.beta.
// ---------------------------------------------------------------------------
__global__ __launch_bounds__(256) void k_prepv(
    const float* __restrict__ val_w, const float* __restrict__ gamma,
    const float* __restrict__ beta, u16* __restrict__ VGc,
    float* __restrict__ Wg1, float* __restrict__ Wb1)
{
    int t = threadIdx.x;
    int e = blockIdx.x * 4 + (t >> 6);
    int lane = t & 63;
    float4 w  = *(const float4*)(val_w + (size_t)e * C_ + lane * 4);
    float4 g  = *(const float4*)(gamma + lane * 4);
    float4 bt = *(const float4*)(beta + lane * 4);
    u16 h0 = f32_to_bf16(w.x * g.x);
    u16 h1 = f32_to_bf16(w.y * g.y);
    u16 h2 = f32_to_bf16(w.z * g.z);
    u16 h3 = f32_to_bf16(w.w * g.w);
    uint2 pk;
    pk.x = pk2(h0, h1);
    pk.y = pk2(h2, h3);
    *(uint2*)(VGc + (size_t)e * C_ + lane * 4) = pk;
    float sg = bf16_to_f32(h0) + bf16_to_f32(h1) + bf16_to_f32(h2) + bf16_to_f32(h3);
    float sb = w.x * bt.x + w.y * bt.y + w.z * bt.z + w.w * bt.w;
    #pragma unroll
    for (int off = 1; off < 64; off <<= 1) {
        sg += __shfl_xor(sg, off);
        sb += __shfl_xor(sb, off);
    }
    if (lane == 0) { Wg1[e] = sg; Wb1[e] = sb; }
}

// ---------------------------------------------------------------------------
// k_fused (8-wave rev): per (ks,b) block of 512 threads over a 512-l slice,
// chunked by 32 l. Per chunk, 3 phases:
//   A: write XC(k) from pr, stats from XT(k)            | barrier
//   B: logits MFMA -> exp -> EA; cvt fr->pr; load k+2   | barrier
//   C: GEMM (EA x XC) into acc; write XT(k+1) from pr   | barrier
// acc[4][4] per lane (64 VGPR).
// __launch_bounds__(512, 2): observed toolchain semantics = min BLOCKS/CU
// (R2: arg 4 with 8-wave blocks -> VGPR_Count 64 -> catastrophic acc spill).
// arg 2 -> 16-wave cap -> 128 VGPR budget, fits the ~120-reg live set.
// XC single-buffered; LDS pool 41.5 KB. Epilogue projects Praw -> Apart via
// VGc MFMA in two 64-row halves (P reuses the pool).
// ---------------------------------------------------------------------------
__global__ __launch_bounds__(512, 2) void k_fused(
    const float* __restrict__ x, const u16* __restrict__ wc,
    const float* __restrict__ Swg, const float* __restrict__ Cb,
    const u16* __restrict__ VGc, float* __restrict__ Apart,
    float* __restrict__ DenP, float* __restrict__ SnuP)
{
    // pool: main loop {XT 16896 | EA 9216 | XC 16384} = 42496 B
    //       epilogue  {P 64*264*2 = 33792 B} (reuse)
    __shared__ __align__(16) char POOL[42496];
    u16* const XT = (u16*)POOL;            // [32][264]
    u16* const EA = (u16*)(POOL + 16896);  // [128][36]
    u16* const XC = (u16*)(POOL + 26112);  // [256][32] swizzled
    __shared__ float smu[32], srs[32];
    int t = threadIdx.x;
    int lane = t & 63, wv = t >> 6;        // wv 0..7
    int lane15 = lane & 15, quad = lane >> 4;
    int ks = blockIdx.x, b = blockIdx.y;
    int lbase = ks * 512;
    int m0 = (wv & 1) * 64, n0 = (wv >> 1) * 64;
    int c_own = t & 255, hh = t >> 8;      // staging: channel + l-half

    // logits constants: one head per wave
    int h = wv;
    bf16x8 af = *(const bf16x8*)(wc + (size_t)(h * 16 + lane15) * DH + quad * 8);
    float swr[4], cbr[4];
    #pragma unroll
    for (int r = 0; r < 4; r++) {
        int hq = h * 16 + quad * 4 + r;
        swr[r] = Swg[hq];
        cbr[r] = Cb[hq];
    }

    const float* xR = x + ((size_t)b * C_ + c_own) * L_ + lbase + hh * 16;

    float4 fr[4];       // fp32 prefetch: 16 l of channel c_own
    uint4 pr[2];        // packed bf16 for one chunk (16 l)
    auto loadregs = [&](int k) {
        #pragma unroll
        for (int i = 0; i < 4; i++) fr[i] = *(const float4*)(xR + k * 32 + i * 4);
    };
    auto cvtregs = [&]() {
        const float* pf = (const float*)fr;
        u16 hb[16];
        #pragma unroll
        for (int e = 0; e < 16; e++) hb[e] = f32_to_bf16(pf[e]);
        #pragma unroll
        for (int i = 0; i < 2; i++) {
            uint4 w;
            w.x = pk2(hb[i * 8 + 0], hb[i * 8 + 1]);
            w.y = pk2(hb[i * 8 + 2], hb[i * 8 + 3]);
            w.z = pk2(hb[i * 8 + 4], hb[i * 8 + 5]);
            w.w = pk2(hb[i * 8 + 6], hb[i * 8 + 7]);
            pr[i] = w;
        }
    };
    auto write_xc = [&]() {
        #pragma unroll
        for (int i = 0; i < 2; i++) {
            int g = hh * 2 + i;
            *(uint4*)&XC[c_own * 32 + ((g ^ ((c_own >> 1) & 3)) * 8)] = pr[i];
        }
    };
    auto write_xt = [&]() {
        const u16* ph = (const u16*)pr;
        #pragma unroll
        for (int e = 0; e < 16; e++) XT[(hh * 16 + e) * 264 + c_own] = ph[e];
    };

    f32x4 acc[4][4];
    #pragma unroll
    for (int i = 0; i < 4; i++)
        #pragma unroll
        for (int j = 0; j < 4; j++) {
            f32x4 z = {0.f, 0.f, 0.f, 0.f};
            acc[i][j] = z;
        }
    float se[4] = {}, sm[4] = {};

    int l_loc = t >> 4, g16 = t & 15;   // stats: 16 threads per l

    loadregs(0);
    cvtregs();          // pr = chunk 0
    write_xt();         // XT(0)
    loadregs(1);        // fr = chunk 1
    __syncthreads();

    for (int k = 0; k < 16; k++) {
        // ---- phase A: XC(k) from pr; stats(k) from XT ----
        write_xc();
        {
            const u16* row = XT + l_loc * 264 + g16 * 16;
            float s = 0.f, q = 0.f;
            #pragma unroll
            for (int j = 0; j < 2; j++) {
                uint4 v = *(const uint4*)(row + j * 8);
                u32 ww[4] = {v.x, v.y, v.z, v.w};
                #pragma unroll
                for (int e = 0; e < 4; e++) {
                    float f0 = __uint_as_float(ww[e] << 16);
                    float f1 = __uint_as_float(ww[e] & 0xffff0000u);
                    s += f0 + f1;
                    q += f0 * f0 + f1 * f1;
                }
            }
            #pragma unroll
            for (int off = 1; off < 16; off <<= 1) {
                s += __shfl_xor(s, off);
                q += __shfl_xor(q, off);
            }
            if (g16 == 0) {
                float mm = s * (1.f / C_);
                float vv = fmaxf(q * (1.f / C_) - mm * mm, 0.f) + EPS_;
                smu[l_loc] = mm;
                srs[l_loc] = rsqrtf(vv);
            }
        }
        __syncthreads();

        // ---- phase B: logits MFMA -> exp -> EA; cvt + prefetch ----
        #pragma unroll
        for (int half = 0; half < 2; half++) {
            float m_l = smu[half * 16 + lane15];
            float r_l = srs[half * 16 + lane15];
            bf16x8 bfrag = *(const bf16x8*)(XT + (half * 16 + lane15) * 264 + h * DH + quad * 8);
            f32x4 z = {0.f, 0.f, 0.f, 0.f};
            f32x4 c4 = __builtin_amdgcn_mfma_f32_16x16x32_bf16(af, bfrag, z, 0, 0, 0);
            #pragma unroll
            for (int r = 0; r < 4; r++) {
                float logit = r_l * (c4[r] - m_l * swr[r]) + cbr[r];
                float e = __expf(logit);     // logits ~N(0,1): no max-sub needed
                float ers = e * r_l;
                EA[(h * 16 + quad * 4 + r) * 36 + half * 16 + lane15] = f32_to_bf16(ers);
                se[r] += e;
                sm[r] += ers * m_l;
            }
        }
        if (k < 15) cvtregs();          // pr = chunk k+1
        if (k < 14) loadregs(k + 2);    // fr = chunk k+2
        __syncthreads();

        // ---- phase C: GEMM(k) + stage XT(k+1) ----
        bf16x8 a[4];
        #pragma unroll
        for (int i = 0; i < 4; i++)
            a[i] = *(const bf16x8*)&EA[(m0 + i * 16 + lane15) * 36 + quad * 8];
        #pragma unroll
        for (int j = 0; j < 4; j++) {
            int row = n0 + j * 16 + lane15;
            bf16x8 bbj = *(const bf16x8*)&XC[row * 32 + ((quad ^ ((row >> 1) & 3)) * 8)];
            #pragma unroll
            for (int i = 0; i < 4; i++)
                acc[i][j] = __builtin_amdgcn_mfma_f32_16x16x32_bf16(a[i], bbj, acc[i][j], 0, 0, 0);
        }
        if (k < 15) write_xt();         // XT(k+1)
        __syncthreads();
    }

    // ---- epilogue: Praw -> bf16 P (two 64-row halves) -> MFMA VGc -> Apart
    u16* const P = (u16*)POOL;   // [64][264], reuses the whole pool
    float* ApB = Apart + (((size_t)ks * B_ + b) * HQ) * DH;
    #pragma unroll
    for (int half = 0; half < 2; half++) {
        if ((wv & 1) == half) {
            #pragma unroll
            for (int i = 0; i < 4; i++)
                #pragma unroll
                for (int j = 0; j < 4; j++) {
                    int lr = i * 16 + quad * 4;
                    int col = n0 + j * 16 + lane15;
                    #pragma unroll
                    for (int r = 0; r < 4; r++)
                        P[(lr + r) * 264 + col] = f32_to_bf16(acc[i][j][r]);
                }
        }
        __syncthreads();
        {
            int hl = wv >> 1;                 // 0..3
            int he = half * 4 + hl;           // head for this task
            int dt = wv & 1;                  // d-tile
            f32x4 c2 = {0.f, 0.f, 0.f, 0.f};
            #pragma unroll
            for (int kk = 0; kk < 8; kk++) {
                bf16x8 a = *(const bf16x8*)&P[(hl * 16 + lane15) * 264 + kk * 32 + quad * 8];
                bf16x8 vg = *(const bf16x8*)(VGc + (size_t)(he * DH + dt * 16 + lane15) * C_ + kk * 32 + quad * 8);
                c2 = __builtin_amdgcn_mfma_f32_16x16x32_bf16(a, vg, c2, 0, 0, 0);
            }
            #pragma unroll
            for (int r = 0; r < 4; r++)
                ApB[(size_t)(he * 16 + quad * 4 + r) * DH + dt * 16 + lane15] = c2[r];
        }
        __syncthreads();
    }

    // ---- softmax partial sums: reduce over lane15, one store per row ----
    #pragma unroll
    for (int r = 0; r < 4; r++) {
        float v = se[r], w = sm[r];
        #pragma unroll
        for (int off = 1; off < 16; off <<= 1) {
            v += __shfl_xor(v, off);
            w += __shfl_xor(w, off);
        }
        if (lane15 == 0) {
            int row = b * HQ + wv * 16 + quad * 4 + r;
            DenP[ks * (B_ * HQ) + row] = v;
            SnuP[ks * (B_ * HQ) + row] = w;
        }
    }
}

// ---------------------------------------------------------------------------
// k_reduce: A[b][hq][d] = (sum_s Apart - SnuTot*Wg1[hd]) / DenTot
//           + Wb1[hd] + val_b[hd]       (beta term: se/den == 1)
// ---------------------------------------------------------------------------
__global__ __launch_bounds__(256) void k_reduce(
    const float* __restrict__ Apart, const float* __restrict__ DenP,
    const float* __restrict__ SnuP, const float* __restrict__ Wg1,
    const float* __restrict__ Wb1, const float* __restrict__ val_b,
    float* __restrict__ A)
{
    __shared__ float sden[32], ssnu[32];
    int t = threadIdx.x;
    int q4 = blockIdx.x, b = blockIdx.y;
    int hq0 = q4 * 32;
    if (t < 32) {
        int row = b * HQ + hq0 + t;
        float d = 0.f, sn = 0.f;
        #pragma unroll
        for (int s = 0; s < 8; s++) {
            d  += DenP[s * (B_ * HQ) + row];
            sn += SnuP[s * (B_ * HQ) + row];
        }
        sden[t] = d;
        ssnu[t] = sn;
    }
    __syncthreads();
    #pragma unroll
    for (int i = 0; i < 4; i++) {
        int idx = i * 256 + t;
        int r32 = idx >> 5, d = idx & 31;
        int hq = hq0 + r32;
        float v = 0.f;
        #pragma unroll
        for (int s = 0; s < 8; s++)
            v += Apart[(((size_t)s * B_ + b) * HQ + hq) * DH + d];
        int hd = (hq >> 4) * DH + d;
        A[((size_t)b * HQ + hq) * DH + d] =
            (v - ssnu[r32] * Wg1[hd]) / sden[r32] + Wb1[hd] + val_b[hd];
    }
}

// ---------------------------------------------------------------------------
// k_final: out[b][f] = sum_j A[b][j]*fin_w[f][j] + fin_b[f]
// grid (32,16), block 256; k-split atomicAdd (out pre-zeroed).
// ---------------------------------------------------------------------------
__global__ __launch_bounds__(256) void k_final(
    const float* __restrict__ A, const float* __restrict__ fin_w,
    const float* __restrict__ fin_b, float* __restrict__ out)
{
    __shared__ float At[64 * 129];
    __shared__ float Fw[32 * 129];
    int t = threadIdx.x;
    int kc = blockIdx.x, ft = blockIdx.y;
    int k0 = kc * 128;

    #pragma unroll
    for (int w = 0; w < 8; w++) {
        int s = t + w * 256;
        int row = s >> 5, seg = s & 31;
        float4 v = *(const float4*)(A + (size_t)row * 4096 + k0 + seg * 4);
        const float* pf = (const float*)&v;
        #pragma unroll
        for (int e = 0; e < 4; e++) At[row * 129 + seg * 4 + e] = pf[e];
    }
    #pragma unroll
    for (int w = 0; w < 4; w++) {
        int s = t + w * 256;
        int row = s >> 5, seg = s & 31;
        float4 v = *(const float4*)(fin_w + (size_t)(ft * 32 + row) * 4096 + k0 + seg * 4);
        const float* pf = (const float*)&v;
        #pragma unroll
        for (int e = 0; e < 4; e++) Fw[row * 129 + seg * 4 + e] = pf[e];
    }
    __syncthreads();

    int tb = t >> 3, tf = t & 7;
    float acc[2][4];
    #pragma unroll
    for (int e = 0; e < 2; e++)
        #pragma unroll
        for (int j = 0; j < 4; j++) acc[e][j] = 0.f;

    for (int k = 0; k < 128; k++) {
        float a0 = At[(tb * 2) * 129 + k];
        float a1 = At[(tb * 2 + 1) * 129 + k];
        #pragma unroll
        for (int j = 0; j < 4; j++) {
            float f = Fw[(tf * 4 + j) * 129 + k];
            acc[0][j] += a0 * f;
            acc[1][j] += a1 * f;
        }
    }
    #pragma unroll
    for (int e = 0; e < 2; e++) {
        int brow = tb * 2 + e;
        #pragma unroll
        for (int j = 0; j < 4; j++) {
            int f = ft * 32 + tf * 4 + j;
            float v = acc[e][j];
            if (kc == 0) v += fin_b[f];
            atomicAdd(&out[(size_t)brow * FHN + f], v);
        }
    }
}

extern "C" void kernel_launch(void* const* d_in, const int* in_sizes, int n_in,
                              void* d_out, int out_size, void* d_ws, size_t ws_size,
                              hipStream_t stream) {
    const float* x      = (const float*)d_in[0];
    const float* gamma  = (const float*)d_in[1];
    const float* beta   = (const float*)d_in[2];
    const float* attn_w = (const float*)d_in[3];
    const float* val_w  = (const float*)d_in[4];
    const float* val_b  = (const float*)d_in[5];
    const float* fin_w  = (const float*)d_in[6];
    const float* fin_b  = (const float*)d_in[7];
    float* out = (float*)d_out;
    char* ws = (char*)d_ws;

    u16*   wc    = (u16*)(ws + WS_WC);
    float* Swg   = (float*)(ws + WS_SWG);
    float* Cb    = (float*)(ws + WS_CB);
    u16*   VGc   = (u16*)(ws + WS_VGC);
    float* Wg1   = (float*)(ws + WS_WG1);
    float* Wb1   = (float*)(ws + WS_WB1);
    float* DenP  = (float*)(ws + WS_DENP);
    float* SnuP  = (float*)(ws + WS_SNUP);
    float* A     = (float*)(ws + WS_A);
    float* Apart = (float*)(ws + WS_APART);

    hipMemsetAsync(out, 0, (size_t)B_ * FHN * sizeof(float), stream);

    k_prep<<<dim3(1), dim3(256), 0, stream>>>(attn_w, gamma, beta, wc, Swg, Cb);
    k_prepv<<<dim3(64), dim3(256), 0, stream>>>(val_w, gamma, beta, VGc, Wg1, Wb1);
    k_fused<<<dim3(8, 64), dim3(512), 0, stream>>>(x, wc, Swg, Cb, VGc, Apart,
                                                   DenP, SnuP);
    k_reduce<<<dim3(4, 64), dim3(256), 0, stream>>>(Apart, DenP, SnuP, Wg1, Wb1,
                                                    val_b, A);
    k_final<<<dim3(32, 16), dim3(256), 0, stream>>>(A, fin_w, fin_b, out);
}